// Round 1
// baseline (554.446 us; speedup 1.0000x reference)
//
#include <hip/hip_runtime.h>
#include <math.h>

#define NDIM 64

// K1: one wave per edge. lane d handles dimension d.
// Computes logit[e] and compacts (vi, vj) into an int2 array.
__global__ void __launch_bounds__(256)
k1_logits(const int* __restrict__ edges,
          const float* __restrict__ h,
          const float* __restrict__ pw,
          const float* __restrict__ nw,
          float* __restrict__ logit,
          int2* __restrict__ vivj,
          int n_edges) {
    const int lane = threadIdx.x & 63;
    const int wave_in_block = threadIdx.x >> 6;
    const int waves_per_block = blockDim.x >> 6;
    int wid = blockIdx.x * waves_per_block + wave_in_block;
    const int wstride = gridDim.x * waves_per_block;

    // weight rows: constant per lane across the whole edge loop
    const float pw0 = pw[lane], pw1 = pw[64 + lane], pw2 = pw[128 + lane];
    const float nw0 = nw[lane], nw1 = nw[64 + lane], nw2 = nw[128 + lane];

    for (int e = wid; e < n_edges; e += wstride) {
        const int vi = edges[e * 8 + 1];
        const int vj = edges[e * 8 + 2];
        const float a = h[vi * NDIM + lane];
        const float b = h[vj * NDIM + lane];
        const float pa = fmaxf(a, 0.f), na = fmaxf(-a, 0.f);
        const float pb = fmaxf(b, 0.f), nb = fmaxf(-b, 0.f);
        float c = pa * pw0 + pb * pw1 + pa * pb * pw2
                - na * nw0 - nb * nw1 - na * nb * nw2;
        // 64-lane wave reduction
        #pragma unroll
        for (int m = 32; m >= 1; m >>= 1) c += __shfl_xor(c, m, 64);
        if (lane == 0) {
            logit[e] = c;
            vivj[e] = make_int2(vi, vj);
        }
    }
}

// K2: one thread per node. vi is sorted -> contiguous segment found by
// binary search; compute segment max and sum(exp).
__global__ void __launch_bounds__(256)
k2_segstats(const int2* __restrict__ vivj,
            const float* __restrict__ logit,
            float* __restrict__ segmax,
            float* __restrict__ denom,
            int n_edges, int n_nodes) {
    const int n = blockIdx.x * blockDim.x + threadIdx.x;
    if (n >= n_nodes) return;

    // lower_bound over vivj[].x
    int lo = 0, hi = n_edges;
    while (lo < hi) { int mid = (lo + hi) >> 1; if (vivj[mid].x < n) lo = mid + 1; else hi = mid; }
    const int beg = lo;
    hi = n_edges;
    while (lo < hi) { int mid = (lo + hi) >> 1; if (vivj[mid].x < n + 1) lo = mid + 1; else hi = mid; }
    const int end = lo;

    float m = -INFINITY;
    for (int e = beg; e < end; ++e) m = fmaxf(m, logit[e]);
    float s = 0.f;
    for (int e = beg; e < end; ++e) s += __expf(logit[e] - m);
    segmax[n] = m;
    denom[n]  = (end > beg) ? s : 1.f;
}

// K3: one wave per edge; lane d scatters dimension d into out[vj].
__global__ void __launch_bounds__(256)
k3_scatter(const int2* __restrict__ vivj,
           const float* __restrict__ logit,
           const float* __restrict__ segmax,
           const float* __restrict__ denom,
           const float* __restrict__ h,
           float* __restrict__ out,
           int n_edges) {
    const int lane = threadIdx.x & 63;
    const int wave_in_block = threadIdx.x >> 6;
    const int waves_per_block = blockDim.x >> 6;
    int wid = blockIdx.x * waves_per_block + wave_in_block;
    const int wstride = gridDim.x * waves_per_block;

    for (int e = wid; e < n_edges; e += wstride) {
        const int2 v = vivj[e];
        const float attn = __expf(logit[e] - segmax[v.x]) / denom[v.x];
        const float val = attn * h[v.x * NDIM + lane];
        atomicAdd(&out[v.y * NDIM + lane], val);
    }
}

extern "C" void kernel_launch(void* const* d_in, const int* in_sizes, int n_in,
                              void* d_out, int out_size, void* d_ws, size_t ws_size,
                              hipStream_t stream) {
    const float* h   = (const float*)d_in[0];
    const float* pw  = (const float*)d_in[1];
    const float* nw  = (const float*)d_in[2];
    const int* edges = (const int*)d_in[3];
    float* out = (float*)d_out;

    const int n_nodes = in_sizes[0] / NDIM;
    const int n_edges = in_sizes[3] / 8;

    char* ws = (char*)d_ws;
    float* logit  = (float*)ws;                                   // n_edges f32
    int2*  vivj   = (int2*)(ws + (size_t)n_edges * 4);            // n_edges int2
    float* segmax = (float*)(ws + (size_t)n_edges * 12);          // n_nodes f32
    float* denom  = segmax + n_nodes;                             // n_nodes f32

    hipMemsetAsync(d_out, 0, (size_t)out_size * sizeof(float), stream);

    k1_logits<<<2048, 256, 0, stream>>>(edges, h, pw, nw, logit, vivj, n_edges);
    k2_segstats<<<(n_nodes + 255) / 256, 256, 0, stream>>>(vivj, logit, segmax, denom, n_edges, n_nodes);
    k3_scatter<<<2048, 256, 0, stream>>>(vivj, logit, segmax, denom, h, out, n_edges);
}

// Round 2
// 484.869 us; speedup vs baseline: 1.1435x; 1.1435x over previous
//
#include <hip/hip_runtime.h>
#include <math.h>

#define NDIM 64

__device__ __forceinline__ float wave_sum64(float c) {
    #pragma unroll
    for (int m = 32; m >= 1; m >>= 1) c += __shfl_xor(c, m, 64);
    return c;
}

// K1: one wave per edge. lane d handles dim d. Computes logit[e],
// optionally compacts (vi,vj), and histograms vj into hist[].
template <bool FAT>
__global__ void __launch_bounds__(256)
k1_logits(const int* __restrict__ edges,
          const float* __restrict__ h,
          const float* __restrict__ pw,
          const float* __restrict__ nw,
          float* __restrict__ logit,
          int* __restrict__ vivj,     // FAT only: 2*E ints
          int* __restrict__ hist,     // n_nodes ints, pre-zeroed
          int n_edges) {
    const int lane = threadIdx.x & 63;
    const int wib  = threadIdx.x >> 6;
    const int wpb  = blockDim.x >> 6;
    int wid = blockIdx.x * wpb + wib;
    const int wstride = gridDim.x * wpb;

    const float pw0 = pw[lane], pw1 = pw[64 + lane], pw2 = pw[128 + lane];
    const float nw0 = nw[lane], nw1 = nw[64 + lane], nw2 = nw[128 + lane];

    for (int e = wid; e < n_edges; e += wstride) {
        const int vi = edges[e * 8 + 1];
        const int vj = edges[e * 8 + 2];
        const float a = h[vi * NDIM + lane];
        const float b = h[vj * NDIM + lane];
        const float pa = fmaxf(a, 0.f), na = fmaxf(-a, 0.f);
        const float pb = fmaxf(b, 0.f), nb = fmaxf(-b, 0.f);
        float c = pa * pw0 + pb * pw1 + pa * pb * pw2
                - na * nw0 - nb * nw1 - na * nb * nw2;
        c = wave_sum64(c);
        if (lane == 0) {
            logit[e] = c;
            if (FAT) { vivj[2 * e] = vi; vivj[2 * e + 1] = vj; }
            atomicAdd(&hist[vj], 1);
        }
    }
}

// K2: thread per node; vi is sorted -> binary search for the segment,
// then segment max and sum(exp). viarr is strided: vi at viarr[e*stride].
__global__ void __launch_bounds__(256)
k2_segstats(const int* __restrict__ viarr, int stride,
            const float* __restrict__ logit,
            float* __restrict__ segmax, float* __restrict__ denom,
            int n_edges, int n_nodes) {
    const int n = blockIdx.x * blockDim.x + threadIdx.x;
    if (n >= n_nodes) return;
    int lo = 0, hi = n_edges;
    while (lo < hi) { int mid = (lo + hi) >> 1; if (viarr[(size_t)mid * stride] < n) lo = mid + 1; else hi = mid; }
    const int beg = lo;
    hi = n_edges;
    while (lo < hi) { int mid = (lo + hi) >> 1; if (viarr[(size_t)mid * stride] < n + 1) lo = mid + 1; else hi = mid; }
    const int end = lo;

    float m = -INFINITY;
    for (int e = beg; e < end; ++e) m = fmaxf(m, logit[e]);
    float s = 0.f;
    for (int e = beg; e < end; ++e) s += __expf(logit[e] - m);
    segmax[n] = m;
    denom[n]  = (end > beg) ? s : 1.f;
}

// ---- exclusive scan over hist (n <= 256*256 entries) ----
__global__ void __launch_bounds__(256)
scan_blocks(int* __restrict__ data, int* __restrict__ bsum, int n) {
    __shared__ int sm[256];
    const int t = threadIdx.x;
    const int i = blockIdx.x * 256 + t;
    int v = (i < n) ? data[i] : 0;
    sm[t] = v;
    __syncthreads();
    int x = v;
    #pragma unroll
    for (int off = 1; off < 256; off <<= 1) {
        int add = (t >= off) ? sm[t - off] : 0;
        __syncthreads();
        x += add; sm[t] = x;
        __syncthreads();
    }
    if (i < n) data[i] = x - v;              // block-local exclusive
    if (t == 255) bsum[blockIdx.x] = x;      // block total
}

__global__ void __launch_bounds__(256)
scan_top(int* __restrict__ bsum, int nb) {
    __shared__ int sm[256];
    const int t = threadIdx.x;
    int v = (t < nb) ? bsum[t] : 0;
    sm[t] = v;
    __syncthreads();
    int x = v;
    #pragma unroll
    for (int off = 1; off < 256; off <<= 1) {
        int add = (t >= off) ? sm[t - off] : 0;
        __syncthreads();
        x += add; sm[t] = x;
        __syncthreads();
    }
    if (t < nb) bsum[t] = x - v;             // exclusive
}

__global__ void __launch_bounds__(256)
scan_add(int* __restrict__ data, const int* __restrict__ bsum, int n, int total) {
    const int i = blockIdx.x * 256 + threadIdx.x;
    if (i < n) data[i] += bsum[blockIdx.x];
    else if (i == n) data[i] = total;        // offs[n_nodes] = n_edges
}

// K3a: thread per edge: compute destination slot in vj-sorted order.
// FAT: store (vi, attn) record. Lean: store edge index only.
template <bool FAT>
__global__ void __launch_bounds__(256)
k3a_scatter(const int* __restrict__ viarr, int stride,
            const float* __restrict__ logit,
            const float* __restrict__ segmax, const float* __restrict__ denom,
            const int* __restrict__ offs, int* __restrict__ cursor,
            int2* __restrict__ rec, int* __restrict__ perm, int n_edges) {
    const int e = blockIdx.x * blockDim.x + threadIdx.x;
    if (e >= n_edges) return;
    const int vi = viarr[(size_t)e * stride];
    const int vj = viarr[(size_t)e * stride + 1];
    const int pos = offs[vj] + atomicAdd(&cursor[vj], 1);
    if (FAT) {
        const float attn = __expf(logit[e] - segmax[vi]) / denom[vi];
        rec[pos] = make_int2(vi, __float_as_int(attn));
    } else {
        perm[pos] = e;
    }
}

// K3b: one wave per destination node; lane d owns dim d. No atomics.
template <bool FAT>
__global__ void __launch_bounds__(256)
k3b_gather(const int2* __restrict__ rec, const int* __restrict__ perm,
           const int* __restrict__ viarr, int stride,
           const float* __restrict__ logit,
           const float* __restrict__ segmax, const float* __restrict__ denom,
           const int* __restrict__ offs,
           const float* __restrict__ h,
           float* __restrict__ out, int n_nodes) {
    const int lane = threadIdx.x & 63;
    const int wib  = threadIdx.x >> 6;
    const int wpb  = blockDim.x >> 6;
    const int n = blockIdx.x * wpb + wib;
    if (n >= n_nodes) return;
    const int beg = offs[n], end = offs[n + 1];
    float acc = 0.f;
    for (int k = beg; k < end; ++k) {
        int vi; float attn;
        if (FAT) {
            const int2 r = rec[k];
            vi = r.x; attn = __int_as_float(r.y);
        } else {
            const int e = perm[k];
            vi = viarr[(size_t)e * stride];
            attn = __expf(logit[e] - segmax[vi]) / denom[vi];
        }
        acc += attn * h[vi * NDIM + lane];
    }
    out[(size_t)n * NDIM + lane] = acc;   // writes zeros for empty nodes too
}

extern "C" void kernel_launch(void* const* d_in, const int* in_sizes, int n_in,
                              void* d_out, int out_size, void* d_ws, size_t ws_size,
                              hipStream_t stream) {
    const float* h   = (const float*)d_in[0];
    const float* pw  = (const float*)d_in[1];
    const float* nw  = (const float*)d_in[2];
    const int* edges = (const int*)d_in[3];
    float* out = (float*)d_out;

    const int n_nodes = in_sizes[0] / NDIM;
    const int n_edges = in_sizes[3] / 8;
    const size_t E = (size_t)n_edges, N = (size_t)n_nodes;

    const size_t need_fat = E * 4 + E * 8 + E * 8 + N * 4 * 3 + (N + 1) * 4 + 4096;
    const bool fat = ws_size >= need_fat;

    char* p = (char*)d_ws;
    float* logit = (float*)p; p += E * 4;
    int* vivj = nullptr; int2* rec = nullptr; int* perm = nullptr;
    if (fat) { vivj = (int*)p; p += E * 8; rec = (int2*)p; p += E * 8; }
    else     { perm = (int*)p; p += E * 4; }
    float* segmax = (float*)p; p += N * 4;
    float* denom  = (float*)p; p += N * 4;
    int* offs     = (int*)p;   p += (N + 1) * 4;   // doubles as hist
    int* cursor   = (int*)p;   p += N * 4;
    int* bsum     = (int*)p;   p += 1024;

    hipMemsetAsync(offs,   0, (N + 1) * 4, stream);
    hipMemsetAsync(cursor, 0, N * 4, stream);

    const int* viarr = fat ? vivj : (edges + 1);
    const int stride = fat ? 2 : 8;

    if (fat) k1_logits<true ><<<2048, 256, 0, stream>>>(edges, h, pw, nw, logit, vivj, offs, n_edges);
    else     k1_logits<false><<<2048, 256, 0, stream>>>(edges, h, pw, nw, logit, nullptr, offs, n_edges);

    k2_segstats<<<(n_nodes + 255) / 256, 256, 0, stream>>>(viarr, stride, logit, segmax, denom, n_edges, n_nodes);

    const int nb = (n_nodes + 255) / 256;   // 196 <= 256 for this problem
    scan_blocks<<<nb, 256, 0, stream>>>(offs, bsum, n_nodes);
    scan_top<<<1, 256, 0, stream>>>(bsum, nb);
    scan_add<<<(n_nodes + 1 + 255) / 256, 256, 0, stream>>>(offs, bsum, n_nodes, n_edges);

    if (fat) k3a_scatter<true ><<<(n_edges + 255) / 256, 256, 0, stream>>>(viarr, stride, logit, segmax, denom, offs, cursor, rec, nullptr, n_edges);
    else     k3a_scatter<false><<<(n_edges + 255) / 256, 256, 0, stream>>>(viarr, stride, logit, segmax, denom, offs, cursor, nullptr, perm, n_edges);

    const int gather_blocks = (n_nodes + 3) / 4;  // 4 waves per 256-thread block
    if (fat) k3b_gather<true ><<<gather_blocks, 256, 0, stream>>>(rec, nullptr, viarr, stride, logit, segmax, denom, offs, h, out, n_nodes);
    else     k3b_gather<false><<<gather_blocks, 256, 0, stream>>>(nullptr, perm, viarr, stride, logit, segmax, denom, offs, h, out, n_nodes);
}